// Round 1
// baseline (300.166 us; speedup 1.0000x reference)
//
#include <hip/hip_runtime.h>

// Problem: x [16,64,224,224] fp32; 2x2 non-overlapping patches -> MLP 4->16(relu)->1
// out [16,64,112,112] fp32.  Memory-bound: 257 MB total traffic, floor ~41 us.

#define NH 112
#define NW 112
#define GPR 28            // float4-output groups per output row (112/4)

__global__ __launch_bounds__(256)
void nn_pool_kernel(const float* __restrict__ x,
                    const float* __restrict__ W1,   // [16][4]
                    const float* __restrict__ b1,   // [16]
                    const float* __restrict__ W2,   // [16]
                    const float* __restrict__ b2,   // [1]
                    float* __restrict__ out,
                    int n_groups)
{
    // Weight loads: kernel-arg base + constant offset -> uniform -> s_load into SGPRs.
    float w10[16], w11[16], w12[16], w13[16], bb1[16], w2[16];
#pragma unroll
    for (int h = 0; h < 16; ++h) {
        w10[h] = W1[4 * h + 0];
        w11[h] = W1[4 * h + 1];
        w12[h] = W1[4 * h + 2];
        w13[h] = W1[4 * h + 3];
        bb1[h] = b1[h];
        w2[h]  = W2[h];
    }
    const float bias2 = b2[0];

    const int stride = gridDim.x * blockDim.x;
    for (int g = blockIdx.x * blockDim.x + threadIdx.x; g < n_groups; g += stride) {
        const int jg = g % GPR;          // which group of 4 patches within the row
        const int t  = g / GPR;
        const int i  = t % NH;           // output row
        const int bc = t / NH;           // fused batch*channel

        const float* row0 = x + (size_t)bc * (224 * 224) + (size_t)(2 * i) * 224 + 8 * jg;
        const float* row1 = row0 + 224;

        const float4 r0a = *reinterpret_cast<const float4*>(row0);
        const float4 r0b = *reinterpret_cast<const float4*>(row0 + 4);
        const float4 r1a = *reinterpret_cast<const float4*>(row1);
        const float4 r1b = *reinterpret_cast<const float4*>(row1 + 4);

        // patch p: [x(2i,2j), x(2i,2j+1), x(2i+1,2j), x(2i+1,2j+1)]
        const float p0x = r0a.x, p0y = r0a.y, p0z = r1a.x, p0w = r1a.y;
        const float p1x = r0a.z, p1y = r0a.w, p1z = r1a.z, p1w = r1a.w;
        const float p2x = r0b.x, p2y = r0b.y, p2z = r1b.x, p2w = r1b.y;
        const float p3x = r0b.z, p3y = r0b.w, p3z = r1b.z, p3w = r1b.w;

        float a0 = bias2, a1 = bias2, a2 = bias2, a3 = bias2;
#pragma unroll
        for (int h = 0; h < 16; ++h) {
            float s0 = fmaf(w10[h], p0x, bb1[h]);
            float s1 = fmaf(w10[h], p1x, bb1[h]);
            float s2 = fmaf(w10[h], p2x, bb1[h]);
            float s3 = fmaf(w10[h], p3x, bb1[h]);
            s0 = fmaf(w11[h], p0y, s0);
            s1 = fmaf(w11[h], p1y, s1);
            s2 = fmaf(w11[h], p2y, s2);
            s3 = fmaf(w11[h], p3y, s3);
            s0 = fmaf(w12[h], p0z, s0);
            s1 = fmaf(w12[h], p1z, s1);
            s2 = fmaf(w12[h], p2z, s2);
            s3 = fmaf(w12[h], p3z, s3);
            s0 = fmaf(w13[h], p0w, s0);
            s1 = fmaf(w13[h], p1w, s1);
            s2 = fmaf(w13[h], p2w, s2);
            s3 = fmaf(w13[h], p3w, s3);
            a0 = fmaf(w2[h], fmaxf(s0, 0.0f), a0);
            a1 = fmaf(w2[h], fmaxf(s1, 0.0f), a1);
            a2 = fmaf(w2[h], fmaxf(s2, 0.0f), a2);
            a3 = fmaf(w2[h], fmaxf(s3, 0.0f), a3);
        }

        float4 res;
        res.x = a0; res.y = a1; res.z = a2; res.w = a3;
        *reinterpret_cast<float4*>(out + (size_t)bc * (NH * NW) + (size_t)i * NW + 4 * jg) = res;
    }
}

extern "C" void kernel_launch(void* const* d_in, const int* in_sizes, int n_in,
                              void* d_out, int out_size, void* d_ws, size_t ws_size,
                              hipStream_t stream) {
    const float* x  = (const float*)d_in[0];
    const float* W1 = (const float*)d_in[1];
    const float* b1 = (const float*)d_in[2];
    const float* W2 = (const float*)d_in[3];
    const float* b2 = (const float*)d_in[4];
    float* out = (float*)d_out;

    const int n_groups = out_size / 4;   // 16*64*112*112 / 4 = 3,211,264
    const int block = 256;
    const int grid = 2048;               // grid-stride; ~8 blocks/CU
    nn_pool_kernel<<<grid, block, 0, stream>>>(x, W1, b1, W2, b2, out, n_groups);
}

// Round 2
// 290.439 us; speedup vs baseline: 1.0335x; 1.0335x over previous
//
#include <hip/hip_runtime.h>

// x [16,64,224,224] fp32 -> 2x2 patches -> MLP 4->16(relu)->1 -> out [16,64,112,112] fp32.
// Memory-bound: 205 MB read + 51 MB write => ~41 us floor at 6.3 TB/s.
//
// Layout trick: with r = img*112 + i (fused image-and-output-row index),
//   input  addr = x   + r*448 + 4*j   (row 2i; +224 for row 2i+1), j in [0,56)
//   output addr = out + r*112 + 2*j
// One thread = one float4 pair = two adjacent patches = one float2 output.
// All loads/stores are lane-contiguous (16 B/lane reads, 8 B/lane writes).

#define NJ 56  // float4 groups per input row = output pairs per output row

__global__ __launch_bounds__(256)
void nn_pool_kernel(const float* __restrict__ x,
                    const float* __restrict__ W1,   // [16][4]
                    const float* __restrict__ b1,   // [16]
                    const float* __restrict__ W2,   // [16]
                    const float* __restrict__ b2,   // [1]
                    float* __restrict__ out,
                    int n_units)
{
    const int tid = blockIdx.x * 256 + threadIdx.x;
    if (tid >= n_units) return;

    const int j = tid % NJ;
    const int r = tid / NJ;          // r = img*112 + i  (no further decomposition needed)

    // Issue the two HBM loads first; weight s_loads and index math hide the latency.
    const float* p0 = x + (size_t)r * 448 + j * 4;
    const float4 t0 = *reinterpret_cast<const float4*>(p0);        // row 2i   : cols 4j..4j+3
    const float4 t1 = *reinterpret_cast<const float4*>(p0 + 224);  // row 2i+1 : cols 4j..4j+3

    // Uniform weight loads -> scalar registers.
    float w0[16], w1[16], w2c[16], w3[16], bb[16], v2[16];
#pragma unroll
    for (int h = 0; h < 16; ++h) {
        w0[h]  = W1[4 * h + 0];
        w1[h]  = W1[4 * h + 1];
        w2c[h] = W1[4 * h + 2];
        w3[h]  = W1[4 * h + 3];
        bb[h]  = b1[h];
        v2[h]  = W2[h];
    }
    const float c2 = b2[0];

    // Patch A = (t0.x, t0.y, t1.x, t1.y), patch B = (t0.z, t0.w, t1.z, t1.w)
    float aA = c2, aB = c2;
#pragma unroll
    for (int h = 0; h < 16; ++h) {
        float sA = fmaf(w0[h], t0.x, bb[h]);
        float sB = fmaf(w0[h], t0.z, bb[h]);
        sA = fmaf(w1[h], t0.y, sA);
        sB = fmaf(w1[h], t0.w, sB);
        sA = fmaf(w2c[h], t1.x, sA);
        sB = fmaf(w2c[h], t1.z, sB);
        sA = fmaf(w3[h], t1.y, sA);
        sB = fmaf(w3[h], t1.w, sB);
        aA = fmaf(v2[h], fmaxf(sA, 0.0f), aA);
        aB = fmaf(v2[h], fmaxf(sB, 0.0f), aB);
    }

    float2 res;
    res.x = aA;
    res.y = aB;
    *reinterpret_cast<float2*>(out + (size_t)r * 112 + j * 2) = res;
}

extern "C" void kernel_launch(void* const* d_in, const int* in_sizes, int n_in,
                              void* d_out, int out_size, void* d_ws, size_t ws_size,
                              hipStream_t stream) {
    const float* x  = (const float*)d_in[0];
    const float* W1 = (const float*)d_in[1];
    const float* b1 = (const float*)d_in[2];
    const float* W2 = (const float*)d_in[3];
    const float* b2 = (const float*)d_in[4];
    float* out = (float*)d_out;

    const int n_units = out_size / 2;              // 6,422,528
    const int block = 256;
    const int grid = (n_units + block - 1) / block; // 25088 exactly
    nn_pool_kernel<<<grid, block, 0, stream>>>(x, W1, b1, W2, b2, out, n_units);
}